// Round 9
// baseline (445.158 us; speedup 1.0000x reference)
//
#include <hip/hip_runtime.h>
#include <cmath>

#define N_TOK 8192
#define DIM 1024

using bf16x8 = __attribute__((ext_vector_type(8))) short;
using f32x4  = __attribute__((ext_vector_type(4))) float;

__device__ __forceinline__ unsigned f2bf(float f) {
  unsigned u = __float_as_uint(f);
  return (u + 0x7fffu + ((u >> 16) & 1u)) >> 16;
}

// width-16 global->LDS DMA; LDS dest = wave-uniform base + lane*16.
__device__ __forceinline__ void gll16(const void* g, void* l) {
  __builtin_amdgcn_global_load_lds(
      (const __attribute__((address_space(1))) void*)g,
      (__attribute__((address_space(3))) void*)l, 16, 0, 0);
}

__global__ __launch_bounds__(1024) void k_setup(const int* __restrict__ tgt,
                                                int* __restrict__ cnt,
                                                int* __restrict__ hoff,
                                                int* __restrict__ perm,
                                                float* __restrict__ psum) {
  __shared__ int base[3];
  int t = threadIdx.x;
  if (t < 3) base[t] = 0;
  __syncthreads();
  for (int i = t; i < N_TOK; i += 1024) {
    int tg = tgt[i];
    int cid = (tg < 10000) ? 0 : (tg < 30000 ? 1 : 2);
    int slot = atomicAdd(&base[cid], 1);
    perm[cid * N_TOK + slot] = i;
  }
  for (int i = t; i < N_TOK; i += 1024) psum[i] = 0.f;
  __syncthreads();
  if (t < 3) cnt[t] = base[t];
  if (t == 0) {
    hoff[0] = 0;
    hoff[1] = base[0] * 1024;
    hoff[2] = base[0] * 1024 + base[1] * 512;
  }
}

// Fused: z==0 -> W fp32->bf16 conversion (HBM-bound);
//        z==1..3 -> hidden GEMM for cid=z-1 (compute-bound). Co-scheduled.
__global__ __launch_bounds__(256) void k_hc(
    const float* __restrict__ x,
    const float* __restrict__ p0, const float* __restrict__ p1, const float* __restrict__ p2,
    const float* __restrict__ w0, const float* __restrict__ w1, const float* __restrict__ w2,
    const int* __restrict__ perm, const int* __restrict__ cnt, const int* __restrict__ hoffs,
    unsigned short* __restrict__ wb, unsigned short* __restrict__ hb) {
  if (blockIdx.z == 0) {
    const int nw0 = 10240000, nw1 = 10240000, nw2 = 5185792;
    const int total4 = (nw0 + nw1 + nw2) >> 2;
    for (int i = blockIdx.x * 256 + threadIdx.x; i < total4; i += 512 * 256) {
      int e = i << 2;
      const float* src;
      if (e < nw0) src = w0 + e;
      else if (e < nw0 + nw1) src = w1 + (e - nw0);
      else src = w2 + (e - nw0 - nw1);
      float4 v = *(const float4*)src;
      uint2 o;
      o.x = f2bf(v.x) | (f2bf(v.y) << 16);
      o.y = f2bf(v.z) | (f2bf(v.w) << 16);
      *(uint2*)(wb + e) = o;
    }
    return;
  }
  // ---- hidden: 128 tokens x 128 dims, BK=32, ping-pong single-barrier ----
  const int cid = blockIdx.z - 1;
  const int pd = (cid == 0) ? 1024 : (cid == 1) ? 512 : 256;
  const int count = cnt[cid];
  if (count == 0) return;
  const int nchd = pd >> 7;
  const int chunk = blockIdx.x % nchd;
  const int tile = blockIdx.x / nchd;
  if (tile * 128 >= count) return;
  const int dim0 = chunk * 128, row0 = tile * 128;
  const float* P = (cid == 0) ? p0 : (cid == 1) ? p1 : p2;
  const size_t hoff = (size_t)hoffs[cid];

  __shared__ char pool[34816];          // stage 4x8KB, aliased by Os (34816B)
  __shared__ int ptoks[128];
  short* stg = (short*)pool;            // [p*8192 + (A:0/B:4096) + ...]
  short* Os = (short*)pool;

  const int t = threadIdx.x, wv = t >> 6, lane = t & 63, m = lane & 15, q = lane >> 4;
  const int wr = wv >> 1, wc = wv & 1;

  if (t < 128) {
    int idx = row0 + t;
    ptoks[t] = perm[cid * N_TOK + min(idx, count - 1)];
  }
  __syncthreads();

  // staging slots: this thread owns slots t and t+256 of each 512-slot region
  const int s0 = t, s1 = t + 256;
  const int r0 = s0 >> 2, g0 = (s0 & 3) ^ ((r0 >> 1) & 3);
  const int r1 = s1 >> 2, g1 = (s1 & 3) ^ ((r1 >> 1) & 3);
  const uint4* srcA0 = (const uint4*)(x + (size_t)ptoks[r0] * DIM) + g0 * 2;
  const uint4* srcA1 = (const uint4*)(x + (size_t)ptoks[r1] * DIM) + g1 * 2;
  const uint4* srcB0 = (const uint4*)(P + (size_t)(dim0 + r0) * DIM) + g0 * 2;
  const uint4* srcB1 = (const uint4*)(P + (size_t)(dim0 + r1) * DIM) + g1 * 2;

  f32x4 acc[4][4];
  #pragma unroll
  for (int rt = 0; rt < 4; ++rt)
    #pragma unroll
    for (int ct = 0; ct < 4; ++ct) acc[rt][ct] = (f32x4){0.f, 0.f, 0.f, 0.f};

  const int sR = (q ^ ((m >> 1) & 3)) * 8;

  // prologue: stage k-step 0 into buf 0
  {
    uint4 a0 = srcA0[0], a1 = srcA0[1], a2 = srcA1[0], a3 = srcA1[1];
    uint4 b0 = srcB0[0], b1 = srcB0[1], b2 = srcB1[0], b3 = srcB1[1];
    uint4 o;
    o.x = (a0.x >> 16) | (a0.y & 0xFFFF0000u); o.y = (a0.z >> 16) | (a0.w & 0xFFFF0000u);
    o.z = (a1.x >> 16) | (a1.y & 0xFFFF0000u); o.w = (a1.z >> 16) | (a1.w & 0xFFFF0000u);
    *(uint4*)&stg[s0 * 8] = o;
    o.x = (a2.x >> 16) | (a2.y & 0xFFFF0000u); o.y = (a2.z >> 16) | (a2.w & 0xFFFF0000u);
    o.z = (a3.x >> 16) | (a3.y & 0xFFFF0000u); o.w = (a3.z >> 16) | (a3.w & 0xFFFF0000u);
    *(uint4*)&stg[s1 * 8] = o;
    o.x = (b0.x >> 16) | (b0.y & 0xFFFF0000u); o.y = (b0.z >> 16) | (b0.w & 0xFFFF0000u);
    o.z = (b1.x >> 16) | (b1.y & 0xFFFF0000u); o.w = (b1.z >> 16) | (b1.w & 0xFFFF0000u);
    *(uint4*)&stg[4096 + s0 * 8] = o;
    o.x = (b2.x >> 16) | (b2.y & 0xFFFF0000u); o.y = (b2.z >> 16) | (b2.w & 0xFFFF0000u);
    o.z = (b3.x >> 16) | (b3.y & 0xFFFF0000u); o.w = (b3.z >> 16) | (b3.w & 0xFFFF0000u);
    *(uint4*)&stg[4096 + s1 * 8] = o;
  }

  int p = 0;
  for (int ks = 0; ks < 32; ++ks) {
    __syncthreads();
    const bool nxt = (ks + 1) < 32;
    uint4 a0, a1, a2, a3, b0, b1, b2, b3;
    if (nxt) {
      int ko = (ks + 1) * 8;
      a0 = srcA0[ko]; a1 = srcA0[ko + 1]; a2 = srcA1[ko]; a3 = srcA1[ko + 1];
      b0 = srcB0[ko]; b1 = srcB0[ko + 1]; b2 = srcB1[ko]; b3 = srcB1[ko + 1];
    }
    short* SAp = stg + p * 8192;
    short* SBp = SAp + 4096;
    bf16x8 af[4];
    #pragma unroll
    for (int rt = 0; rt < 4; ++rt)
      af[rt] = *(bf16x8*)&SAp[(wr * 64 + rt * 16 + m) * 32 + sR];
    #pragma unroll
    for (int ct = 0; ct < 4; ++ct) {
      bf16x8 bb = *(bf16x8*)&SBp[(wc * 64 + ct * 16 + m) * 32 + sR];
      #pragma unroll
      for (int rt = 0; rt < 4; ++rt)
        acc[rt][ct] = __builtin_amdgcn_mfma_f32_16x16x32_bf16(af[rt], bb, acc[rt][ct], 0, 0, 0);
    }
    if (nxt) {
      short* DA = stg + (p ^ 1) * 8192;
      short* DB = DA + 4096;
      uint4 o;
      o.x = (a0.x >> 16) | (a0.y & 0xFFFF0000u); o.y = (a0.z >> 16) | (a0.w & 0xFFFF0000u);
      o.z = (a1.x >> 16) | (a1.y & 0xFFFF0000u); o.w = (a1.z >> 16) | (a1.w & 0xFFFF0000u);
      *(uint4*)&DA[s0 * 8] = o;
      o.x = (a2.x >> 16) | (a2.y & 0xFFFF0000u); o.y = (a2.z >> 16) | (a2.w & 0xFFFF0000u);
      o.z = (a3.x >> 16) | (a3.y & 0xFFFF0000u); o.w = (a3.z >> 16) | (a3.w & 0xFFFF0000u);
      *(uint4*)&DA[s1 * 8] = o;
      o.x = (b0.x >> 16) | (b0.y & 0xFFFF0000u); o.y = (b0.z >> 16) | (b0.w & 0xFFFF0000u);
      o.z = (b1.x >> 16) | (b1.y & 0xFFFF0000u); o.w = (b1.z >> 16) | (b1.w & 0xFFFF0000u);
      *(uint4*)&DB[s0 * 8] = o;
      o.x = (b2.x >> 16) | (b2.y & 0xFFFF0000u); o.y = (b2.z >> 16) | (b2.w & 0xFFFF0000u);
      o.z = (b3.x >> 16) | (b3.y & 0xFFFF0000u); o.w = (b3.z >> 16) | (b3.w & 0xFFFF0000u);
      *(uint4*)&DB[s1 * 8] = o;
    }
    p ^= 1;
  }

  __syncthreads();   // all MFMA LDS reads done; Os aliases stage
  #pragma unroll
  for (int rt = 0; rt < 4; ++rt)
    #pragma unroll
    for (int ct = 0; ct < 4; ++ct)
      #pragma unroll
      for (int rr = 0; rr < 4; ++rr)
        Os[(wr * 64 + rt * 16 + q * 4 + rr) * 136 + wc * 64 + ct * 16 + m] =
            (short)f2bf(acc[rt][ct][rr]);
  __syncthreads();
  {
    int orow = t >> 1, oh = t & 1;
    int slot = row0 + orow;
    if (slot < count) {
      unsigned short* dst = hb + hoff + (size_t)slot * pd + dim0 + oh * 64;
      const short* src = &Os[orow * 136 + oh * 64];
      #pragma unroll
      for (int i = 0; i < 8; ++i)
        *(uint4*)(dst + i * 8) = *(const uint4*)(src + i * 8);
    }
  }
}

// logits+exp-sum+target. 192 tok x 192 col, BK=32 (same 24KB staged and
// 36 MFMA-equiv per barrier as rd8, but -10.7% total block-steps:
// 59.1K vs 66.1K). __launch_bounds__(256,2) pins 2 waves/SIMD
// (acc[6][6]=144 + ~110 arch must fit 256 -- rd5 died at 308 unbounded).
// LDS 48KB -> 2 blocks/CU. rd8's lean body otherwise verbatim.
__global__ __launch_bounds__(256, 2) void k_lse(
    const unsigned short* __restrict__ hb, const unsigned short* __restrict__ wb,
    const float* __restrict__ b0_, const float* __restrict__ b1_, const float* __restrict__ b2_,
    const int* __restrict__ tgt, const int* __restrict__ perm,
    const int* __restrict__ cnt, const int* __restrict__ hoffs,
    float* __restrict__ psum, float* __restrict__ tlog) {
  const int cid = blockIdx.z;
  const int pd     = (cid == 0) ? 1024  : (cid == 1) ? 512   : 256;
  const int cstart = (cid == 0) ? 0     : (cid == 1) ? 10000 : 30000;
  const int csize  = (cid == 0) ? 10000 : (cid == 1) ? 20000 : 20257;
  const size_t woff = (cid == 0) ? 0 : (cid == 1) ? (size_t)10240000 : (size_t)20480000;
  const float* bias = (cid == 0) ? b0_ : (cid == 1) ? b1_ : b2_;
  const int count = cnt[cid];
  if (count == 0) return;
  const unsigned ntile = (unsigned)(count + 191) / 192u;
  const int nchunk = (csize + 191) / 192;
  const int cpx = (nchunk + 7) >> 3;

  const unsigned d = blockIdx.x;
  const int x8 = d & 7;
  const unsigned g = d >> 3;
  const unsigned ci = g / ntile;
  if (ci >= (unsigned)cpx) return;
  const int chunk = x8 * cpx + (int)ci;
  if (chunk >= nchunk) return;
  const int tile = (int)(g - ci * ntile);
  const int col0 = chunk * 192, row0 = tile * 192;
  const size_t hoff = (size_t)hoffs[cid];

  // pool: [0,24576)     = SA (2 bufs x 12KB: 192 rows x 32 k, granules)
  //       [24576,49152) = SB (2 bufs x 12KB: 192 cols x 32 k)
  // First 2KB re-used for ptoks/tlocs after the k-loop.
  __shared__ char pool[49152];
  short* SAs = (short*)pool;
  short* SBs = (short*)(pool + 24576);

  const int t = threadIdx.x, wv = t >> 6, lane = t & 63, m = lane & 15, q = lane >> 4;
  const int wr = wv >> 1, wc = wv & 1;   // wave tile: 96 rows x 96 cols

  // DMA staging instances of 16 rows x 32 k (1KB each): 12 A + 12 B per
  // buffer; wave owns instances {wv*3+i} for both operands.
  const int sub = lane >> 2;
  const int gsw = (lane & 3) ^ ((sub >> 1) & 3);
  const unsigned short *pA[3], *pB[3];
  int aOff[3];
  #pragma unroll
  for (int i = 0; i < 3; ++i) {
    int ia = wv * 3 + i;
    int ra = ia * 16 + sub;
    aOff[i] = ia * 512;
    pA[i] = hb + hoff + (size_t)min(row0 + ra, count - 1) * pd + gsw * 8;
    pB[i] = wb + woff + (size_t)min(col0 + ra, csize - 1) * pd + gsw * 8;
  }

  f32x4 acc[6][6];
  #pragma unroll
  for (int rt = 0; rt < 6; ++rt)
    #pragma unroll
    for (int ct = 0; ct < 6; ++ct) acc[rt][ct] = (f32x4){0.f, 0.f, 0.f, 0.f};

  const int sR = (q ^ ((m >> 1) & 3)) * 8;
  const int nk = pd >> 5;            // BK=32 steps: 32 / 16 / 8

  // prologue: stage k-step 0 into buf 0 (6 gll16 per wave)
  #pragma unroll
  for (int i = 0; i < 3; ++i) {
    gll16(pA[i], SAs + aOff[i]);
    gll16(pB[i], SBs + aOff[i]);
  }

  int p = 0;
  for (int ks = 0; ks < nk; ++ks) {
    __syncthreads();                     // buf p writes landed; prev reads done
    if (ks + 1 < nk) {
      const int ko = (ks + 1) * 32;
      const int bo = (p ^ 1) * 6144;
      #pragma unroll
      for (int i = 0; i < 3; ++i) {
        gll16(pA[i] + ko, SAs + bo + aOff[i]);
        gll16(pB[i] + ko, SBs + bo + aOff[i]);
      }
    }
    const int pb = p * 6144;
    bf16x8 af[6];
    #pragma unroll
    for (int rt = 0; rt < 6; ++rt)
      af[rt] = *(bf16x8*)&SAs[pb + (wr * 96 + rt * 16 + m) * 32 + sR];
    #pragma unroll
    for (int ct = 0; ct < 6; ++ct) {
      bf16x8 bb = *(bf16x8*)&SBs[pb + (wc * 96 + ct * 16 + m) * 32 + sR];
      #pragma unroll
      for (int rt = 0; rt < 6; ++rt)
        acc[rt][ct] = __builtin_amdgcn_mfma_f32_16x16x32_bf16(af[rt], bb, acc[rt][ct], 0, 0, 0);
    }
    p ^= 1;
  }

  // epilogue: token/target lookup via LDS aliased over the (now dead) stage
  __syncthreads();                 // all MFMA LDS reads done
  int* ptoks = (int*)pool;         // 192 ints
  int* tlocs = (int*)(pool + 1024);
  if (t < 192) {
    int idx = row0 + t;
    int tok = perm[cid * N_TOK + min(idx, count - 1)];
    ptoks[t] = tok;
    tlocs[t] = tgt[tok] - cstart;
  }
  __syncthreads();

  float bc[6];
  #pragma unroll
  for (int ct = 0; ct < 6; ++ct)
    bc[ct] = bias[min(col0 + wc * 96 + ct * 16 + m, csize - 1)];

  int tl[6][4];
  #pragma unroll
  for (int rt = 0; rt < 6; ++rt)
    #pragma unroll
    for (int rr = 0; rr < 4; ++rr)
      tl[rt][rr] = tlocs[wr * 96 + rt * 16 + q * 4 + rr];

  float run[6][4] = {{0.f}}, tcap[6][4] = {{0.f}};
  int tfnd[6][4] = {{0}};

  #pragma unroll
  for (int ct = 0; ct < 6; ++ct) {
    int colg = col0 + wc * 96 + ct * 16 + m;
    bool cok = colg < csize;
    #pragma unroll
    for (int rt = 0; rt < 6; ++rt)
      #pragma unroll
      for (int rr = 0; rr < 4; ++rr) {
        float val = acc[rt][ct][rr] + bc[ct];
        if (cok) {
          run[rt][rr] += __expf(val);
          if (tl[rt][rr] == colg) { tcap[rt][rr] = val; tfnd[rt][rr] = 1; }
        }
      }
  }

  #pragma unroll
  for (int rt = 0; rt < 6; ++rt)
    #pragma unroll
    for (int rr = 0; rr < 4; ++rr) {
      float v = run[rt][rr];
      v += __shfl_xor(v, 1, 64);
      v += __shfl_xor(v, 2, 64);
      v += __shfl_xor(v, 4, 64);
      v += __shfl_xor(v, 8, 64);
      int rowl = wr * 96 + rt * 16 + q * 4 + rr;
      if (row0 + rowl < count) {
        int tok = ptoks[rowl];
        if (m == 0) atomicAdd(&psum[tok], v);
        if (tfnd[rt][rr]) tlog[tok] = tcap[rt][rr];
      }
    }
}

__global__ __launch_bounds__(1024) void k_final(const float* __restrict__ psum,
                                                const float* __restrict__ tlog,
                                                float* __restrict__ out) {
  __shared__ float part[16];
  int t = threadIdx.x;
  float s = 0.f;
  for (int n = t; n < N_TOK; n += 1024) {
    float v = __logf(psum[n]) - tlog[n];
    out[1 + n] = v;
    s += v;
  }
  #pragma unroll
  for (int off = 32; off > 0; off >>= 1) s += __shfl_down(s, off, 64);
  if ((t & 63) == 0) part[t >> 6] = s;
  __syncthreads();
  if (t < 64) {
    float v = (t < 16) ? part[t] : 0.f;
    #pragma unroll
    for (int off = 8; off > 0; off >>= 1) v += __shfl_down(v, off, 64);
    if (t == 0) out[0] = v;
  }
}

extern "C" void kernel_launch(void* const* d_in, const int* in_sizes, int n_in,
                              void* d_out, int out_size, void* d_ws, size_t ws_size,
                              hipStream_t stream) {
  const float* x  = (const float*)d_in[0];
  const int* tgt  = (const int*)d_in[1];
  const float* p0 = (const float*)d_in[2];
  const float* w0 = (const float*)d_in[3];
  const float* b0 = (const float*)d_in[4];
  const float* p1 = (const float*)d_in[5];
  const float* w1 = (const float*)d_in[6];
  const float* b1 = (const float*)d_in[7];
  const float* p2 = (const float*)d_in[8];
  const float* w2 = (const float*)d_in[9];
  const float* b2 = (const float*)d_in[10];
  float* out = (float*)d_out;

  char* ws = (char*)d_ws;
  int* cnt            = (int*)(ws + 0);
  int* hoff           = (int*)(ws + 64);
  int* perm           = (int*)(ws + 256);                 // 98,304 B
  unsigned short* wb  = (unsigned short*)(ws + 131072);   // 51,331,584 B
  unsigned short* hb  = (unsigned short*)(ws + 51462656); // 16,777,216 B
  float* psum         = (float*)(ws + 68239872);          // 32,768 B
  float* tlog         = (float*)(ws + 68272640);          // 32,768 B

  k_setup<<<dim3(1), dim3(1024), 0, stream>>>(tgt, cnt, hoff, perm, psum);
  k_hc<<<dim3(512, 1, 4), dim3(256), 0, stream>>>(x, p0, p1, p2, w0, w1, w2,
                                                  perm, cnt, hoff, wb, hb);
  // x = 8 xcd-slots * g; g covers cpx(<=14) * ntile(<=43) -> 4816
  k_lse<<<dim3(4816, 1, 3), dim3(256), 0, stream>>>(hb, wb, b0, b1, b2, tgt, perm, cnt, hoff,
                                                    psum, tlog);
  k_final<<<dim3(1), dim3(1024), 0, stream>>>(psum, tlog, out);
}

// Round 10
// 416.101 us; speedup vs baseline: 1.0698x; 1.0698x over previous
//
#include <hip/hip_runtime.h>
#include <cmath>

#define N_TOK 8192
#define DIM 1024

using bf16x8 = __attribute__((ext_vector_type(8))) short;
using f32x4  = __attribute__((ext_vector_type(4))) float;

__device__ __forceinline__ unsigned f2bf(float f) {
  unsigned u = __float_as_uint(f);
  return (u + 0x7fffu + ((u >> 16) & 1u)) >> 16;
}

// width-16 global->LDS DMA; LDS dest = wave-uniform base + lane*16.
__device__ __forceinline__ void gll16(const void* g, void* l) {
  __builtin_amdgcn_global_load_lds(
      (const __attribute__((address_space(1))) void*)g,
      (__attribute__((address_space(3))) void*)l, 16, 0, 0);
}

__global__ __launch_bounds__(1024) void k_setup(const int* __restrict__ tgt,
                                                int* __restrict__ cnt,
                                                int* __restrict__ hoff,
                                                int* __restrict__ perm,
                                                float* __restrict__ psum) {
  __shared__ int base[3];
  int t = threadIdx.x;
  if (t < 3) base[t] = 0;
  __syncthreads();
  for (int i = t; i < N_TOK; i += 1024) {
    int tg = tgt[i];
    int cid = (tg < 10000) ? 0 : (tg < 30000 ? 1 : 2);
    int slot = atomicAdd(&base[cid], 1);
    perm[cid * N_TOK + slot] = i;
  }
  for (int i = t; i < N_TOK; i += 1024) psum[i] = 0.f;
  __syncthreads();
  if (t < 3) cnt[t] = base[t];
  if (t == 0) {
    hoff[0] = 0;
    hoff[1] = base[0] * 1024;
    hoff[2] = base[0] * 1024 + base[1] * 512;
  }
}

// Fused: z==0 -> W fp32->bf16 conversion (HBM-bound);
//        z==1..3 -> hidden GEMM for cid=z-1 (compute-bound). Co-scheduled.
__global__ __launch_bounds__(256) void k_hc(
    const float* __restrict__ x,
    const float* __restrict__ p0, const float* __restrict__ p1, const float* __restrict__ p2,
    const float* __restrict__ w0, const float* __restrict__ w1, const float* __restrict__ w2,
    const int* __restrict__ perm, const int* __restrict__ cnt, const int* __restrict__ hoffs,
    unsigned short* __restrict__ wb, unsigned short* __restrict__ hb) {
  if (blockIdx.z == 0) {
    const int nw0 = 10240000, nw1 = 10240000, nw2 = 5185792;
    const int total4 = (nw0 + nw1 + nw2) >> 2;
    for (int i = blockIdx.x * 256 + threadIdx.x; i < total4; i += 512 * 256) {
      int e = i << 2;
      const float* src;
      if (e < nw0) src = w0 + e;
      else if (e < nw0 + nw1) src = w1 + (e - nw0);
      else src = w2 + (e - nw0 - nw1);
      float4 v = *(const float4*)src;
      uint2 o;
      o.x = f2bf(v.x) | (f2bf(v.y) << 16);
      o.y = f2bf(v.z) | (f2bf(v.w) << 16);
      *(uint2*)(wb + e) = o;
    }
    return;
  }
  // ---- hidden: 128 tokens x 128 dims, BK=32, ping-pong single-barrier ----
  const int cid = blockIdx.z - 1;
  const int pd = (cid == 0) ? 1024 : (cid == 1) ? 512 : 256;
  const int count = cnt[cid];
  if (count == 0) return;
  const int nchd = pd >> 7;
  const int chunk = blockIdx.x % nchd;
  const int tile = blockIdx.x / nchd;
  if (tile * 128 >= count) return;
  const int dim0 = chunk * 128, row0 = tile * 128;
  const float* P = (cid == 0) ? p0 : (cid == 1) ? p1 : p2;
  const size_t hoff = (size_t)hoffs[cid];

  __shared__ char pool[34816];          // stage 4x8KB, aliased by Os (34816B)
  __shared__ int ptoks[128];
  short* stg = (short*)pool;            // [p*8192 + (A:0/B:4096) + ...]
  short* Os = (short*)pool;

  const int t = threadIdx.x, wv = t >> 6, lane = t & 63, m = lane & 15, q = lane >> 4;
  const int wr = wv >> 1, wc = wv & 1;

  if (t < 128) {
    int idx = row0 + t;
    ptoks[t] = perm[cid * N_TOK + min(idx, count - 1)];
  }
  __syncthreads();

  // staging slots: this thread owns slots t and t+256 of each 512-slot region
  const int s0 = t, s1 = t + 256;
  const int r0 = s0 >> 2, g0 = (s0 & 3) ^ ((r0 >> 1) & 3);
  const int r1 = s1 >> 2, g1 = (s1 & 3) ^ ((r1 >> 1) & 3);
  const uint4* srcA0 = (const uint4*)(x + (size_t)ptoks[r0] * DIM) + g0 * 2;
  const uint4* srcA1 = (const uint4*)(x + (size_t)ptoks[r1] * DIM) + g1 * 2;
  const uint4* srcB0 = (const uint4*)(P + (size_t)(dim0 + r0) * DIM) + g0 * 2;
  const uint4* srcB1 = (const uint4*)(P + (size_t)(dim0 + r1) * DIM) + g1 * 2;

  f32x4 acc[4][4];
  #pragma unroll
  for (int rt = 0; rt < 4; ++rt)
    #pragma unroll
    for (int ct = 0; ct < 4; ++ct) acc[rt][ct] = (f32x4){0.f, 0.f, 0.f, 0.f};

  const int sR = (q ^ ((m >> 1) & 3)) * 8;

  // prologue: stage k-step 0 into buf 0
  {
    uint4 a0 = srcA0[0], a1 = srcA0[1], a2 = srcA1[0], a3 = srcA1[1];
    uint4 b0 = srcB0[0], b1 = srcB0[1], b2 = srcB1[0], b3 = srcB1[1];
    uint4 o;
    o.x = (a0.x >> 16) | (a0.y & 0xFFFF0000u); o.y = (a0.z >> 16) | (a0.w & 0xFFFF0000u);
    o.z = (a1.x >> 16) | (a1.y & 0xFFFF0000u); o.w = (a1.z >> 16) | (a1.w & 0xFFFF0000u);
    *(uint4*)&stg[s0 * 8] = o;
    o.x = (a2.x >> 16) | (a2.y & 0xFFFF0000u); o.y = (a2.z >> 16) | (a2.w & 0xFFFF0000u);
    o.z = (a3.x >> 16) | (a3.y & 0xFFFF0000u); o.w = (a3.z >> 16) | (a3.w & 0xFFFF0000u);
    *(uint4*)&stg[s1 * 8] = o;
    o.x = (b0.x >> 16) | (b0.y & 0xFFFF0000u); o.y = (b0.z >> 16) | (b0.w & 0xFFFF0000u);
    o.z = (b1.x >> 16) | (b1.y & 0xFFFF0000u); o.w = (b1.z >> 16) | (b1.w & 0xFFFF0000u);
    *(uint4*)&stg[4096 + s0 * 8] = o;
    o.x = (b2.x >> 16) | (b2.y & 0xFFFF0000u); o.y = (b2.z >> 16) | (b2.w & 0xFFFF0000u);
    o.z = (b3.x >> 16) | (b3.y & 0xFFFF0000u); o.w = (b3.z >> 16) | (b3.w & 0xFFFF0000u);
    *(uint4*)&stg[4096 + s1 * 8] = o;
  }

  int p = 0;
  for (int ks = 0; ks < 32; ++ks) {
    __syncthreads();
    const bool nxt = (ks + 1) < 32;
    uint4 a0, a1, a2, a3, b0, b1, b2, b3;
    if (nxt) {
      int ko = (ks + 1) * 8;
      a0 = srcA0[ko]; a1 = srcA0[ko + 1]; a2 = srcA1[ko]; a3 = srcA1[ko + 1];
      b0 = srcB0[ko]; b1 = srcB0[ko + 1]; b2 = srcB1[ko]; b3 = srcB1[ko + 1];
    }
    short* SAp = stg + p * 8192;
    short* SBp = SAp + 4096;
    bf16x8 af[4];
    #pragma unroll
    for (int rt = 0; rt < 4; ++rt)
      af[rt] = *(bf16x8*)&SAp[(wr * 64 + rt * 16 + m) * 32 + sR];
    #pragma unroll
    for (int ct = 0; ct < 4; ++ct) {
      bf16x8 bb = *(bf16x8*)&SBp[(wc * 64 + ct * 16 + m) * 32 + sR];
      #pragma unroll
      for (int rt = 0; rt < 4; ++rt)
        acc[rt][ct] = __builtin_amdgcn_mfma_f32_16x16x32_bf16(af[rt], bb, acc[rt][ct], 0, 0, 0);
    }
    if (nxt) {
      short* DA = stg + (p ^ 1) * 8192;
      short* DB = DA + 4096;
      uint4 o;
      o.x = (a0.x >> 16) | (a0.y & 0xFFFF0000u); o.y = (a0.z >> 16) | (a0.w & 0xFFFF0000u);
      o.z = (a1.x >> 16) | (a1.y & 0xFFFF0000u); o.w = (a1.z >> 16) | (a1.w & 0xFFFF0000u);
      *(uint4*)&DA[s0 * 8] = o;
      o.x = (a2.x >> 16) | (a2.y & 0xFFFF0000u); o.y = (a2.z >> 16) | (a2.w & 0xFFFF0000u);
      o.z = (a3.x >> 16) | (a3.y & 0xFFFF0000u); o.w = (a3.z >> 16) | (a3.w & 0xFFFF0000u);
      *(uint4*)&DA[s1 * 8] = o;
      o.x = (b0.x >> 16) | (b0.y & 0xFFFF0000u); o.y = (b0.z >> 16) | (b0.w & 0xFFFF0000u);
      o.z = (b1.x >> 16) | (b1.y & 0xFFFF0000u); o.w = (b1.z >> 16) | (b1.w & 0xFFFF0000u);
      *(uint4*)&DB[s0 * 8] = o;
      o.x = (b2.x >> 16) | (b2.y & 0xFFFF0000u); o.y = (b2.z >> 16) | (b2.w & 0xFFFF0000u);
      o.z = (b3.x >> 16) | (b3.y & 0xFFFF0000u); o.w = (b3.z >> 16) | (b3.w & 0xFFFF0000u);
      *(uint4*)&DB[s1 * 8] = o;
    }
    p ^= 1;
  }

  __syncthreads();   // all MFMA LDS reads done; Os aliases stage
  #pragma unroll
  for (int rt = 0; rt < 4; ++rt)
    #pragma unroll
    for (int ct = 0; ct < 4; ++ct)
      #pragma unroll
      for (int rr = 0; rr < 4; ++rr)
        Os[(wr * 64 + rt * 16 + q * 4 + rr) * 136 + wc * 64 + ct * 16 + m] =
            (short)f2bf(acc[rt][ct][rr]);
  __syncthreads();
  {
    int orow = t >> 1, oh = t & 1;
    int slot = row0 + orow;
    if (slot < count) {
      unsigned short* dst = hb + hoff + (size_t)slot * pd + dim0 + oh * 64;
      const short* src = &Os[orow * 136 + oh * 64];
      #pragma unroll
      for (int i = 0; i < 8; ++i)
        *(uint4*)(dst + i * 8) = *(const uint4*)(src + i * 8);
    }
  }
}

// logits+exp-sum+target. rd8 config (128 tok x 256 col, BK=32,
// __launch_bounds__(256,2), lean body) + DEPTH-2 gll16 pipeline into 3
// LDS buffers with counted vmcnt (T3/T4): each wave waits vmcnt(6) --
// its own buffer-p loads retired, step p+1's 6 stay in flight -- then
// raw s_barrier, then issues step p+2. At this tile the in-flight
// compute (2 blocks x ~400cyc/step x depth 2) covers the ~800cyc DMA
// latency that the rd8 per-step drain exposed. LDS 72KB -> 2 blocks/CU.
__global__ __launch_bounds__(256, 2) void k_lse(
    const unsigned short* __restrict__ hb, const unsigned short* __restrict__ wb,
    const float* __restrict__ b0_, const float* __restrict__ b1_, const float* __restrict__ b2_,
    const int* __restrict__ tgt, const int* __restrict__ perm,
    const int* __restrict__ cnt, const int* __restrict__ hoffs,
    float* __restrict__ psum, float* __restrict__ tlog) {
  const int cid = blockIdx.z;
  const int pd     = (cid == 0) ? 1024  : (cid == 1) ? 512   : 256;
  const int cstart = (cid == 0) ? 0     : (cid == 1) ? 10000 : 30000;
  const int csize  = (cid == 0) ? 10000 : (cid == 1) ? 20000 : 20257;
  const size_t woff = (cid == 0) ? 0 : (cid == 1) ? (size_t)10240000 : (size_t)20480000;
  const float* bias = (cid == 0) ? b0_ : (cid == 1) ? b1_ : b2_;
  const int count = cnt[cid];
  if (count == 0) return;
  const unsigned ntile = (unsigned)(count + 127) >> 7;
  const int nchunk = (csize + 255) >> 8;
  const int cpx = (nchunk + 7) >> 3;

  const unsigned d = blockIdx.x;
  const int x8 = d & 7;
  const unsigned g = d >> 3;
  const unsigned ci = g / ntile;
  if (ci >= (unsigned)cpx) return;
  const int chunk = x8 * cpx + (int)ci;
  if (chunk >= nchunk) return;
  const int tile = (int)(g - ci * ntile);
  const int col0 = chunk * 256, row0 = tile * 128;
  const size_t hoff = (size_t)hoffs[cid];

  // pool: [0,24576)     = SA (3 bufs x 8KB : 128 rows x 32 k, granules)
  //       [24576,73728) = SB (3 bufs x 16KB: 256 cols x 32 k)
  // First 2KB re-used for ptoks/tlocs after the k-loop.
  __shared__ char pool[73728];
  short* SAs = (short*)pool;
  short* SBs = (short*)(pool + 24576);

  const int t = threadIdx.x, wv = t >> 6, lane = t & 63, m = lane & 15, q = lane >> 4;
  const int wr = wv >> 1, wc = wv & 1;   // wave tile: 64 rows x 128 cols

  // DMA staging instances of 16 rows x 32 k (1KB each):
  // A: 8/buffer, wave owns {wv*2+i}; B: 16/buffer, wave owns {wv*4+j}.
  const int sub = lane >> 2;
  const int gsw = (lane & 3) ^ ((sub >> 1) & 3);
  const unsigned short *pA[2], *pB[4];
  int aOff[2], bOff[4];
  #pragma unroll
  for (int i = 0; i < 2; ++i) {
    int ia = wv * 2 + i;
    int ra = ia * 16 + sub;
    aOff[i] = ia * 512;
    pA[i] = hb + hoff + (size_t)min(row0 + ra, count - 1) * pd + gsw * 8;
  }
  #pragma unroll
  for (int j = 0; j < 4; ++j) {
    int ib = wv * 4 + j;
    int rb = ib * 16 + sub;
    bOff[j] = ib * 512;
    pB[j] = wb + woff + (size_t)min(col0 + rb, csize - 1) * pd + gsw * 8;
  }

  f32x4 acc[4][8];
  #pragma unroll
  for (int rt = 0; rt < 4; ++rt)
    #pragma unroll
    for (int ct = 0; ct < 8; ++ct) acc[rt][ct] = (f32x4){0.f, 0.f, 0.f, 0.f};

  const int sR = (q ^ ((m >> 1) & 3)) * 8;
  const int nk = pd >> 5;            // BK=32 steps: 32 / 16 / 8

  // depth-2 prologue: step 0 -> buf 0, step 1 -> buf 1 (12 loads/wave,
  // step-0's 6 first so vmcnt(6) at ks=0 retires exactly step 0)
  #pragma unroll
  for (int i = 0; i < 2; ++i) gll16(pA[i], SAs + aOff[i]);
  #pragma unroll
  for (int j = 0; j < 4; ++j) gll16(pB[j], SBs + bOff[j]);
  #pragma unroll
  for (int i = 0; i < 2; ++i) gll16(pA[i] + 32, SAs + 4096 + aOff[i]);
  #pragma unroll
  for (int j = 0; j < 4; ++j) gll16(pB[j] + 32, SBs + 8192 + bOff[j]);

  int p = 0;
  for (int ks = 0; ks < nk; ++ks) {
    // Wait own loads of buffer p (6 of step ks retire; step ks+1's 6
    // stay in flight). Every wave does this BEFORE the barrier, so after
    // the barrier all waves' buffer-p data is in LDS.
    if (ks + 1 < nk) asm volatile("s_waitcnt vmcnt(6)" ::: "memory");
    else             asm volatile("s_waitcnt vmcnt(0)" ::: "memory");
    __builtin_amdgcn_s_barrier();
    asm volatile("" ::: "memory");
    if (ks + 2 < nk) {
      // buffer (p+2)%3 was read at step ks-1; its readers consumed via
      // lgkm waits before the barrier above -> safe to overwrite.
      const int ko = (ks + 2) * 32;
      const int pn = (p == 0) ? 2 : p - 1;   // (p+2)%3
      #pragma unroll
      for (int i = 0; i < 2; ++i) gll16(pA[i] + ko, SAs + pn * 4096 + aOff[i]);
      #pragma unroll
      for (int j = 0; j < 4; ++j) gll16(pB[j] + ko, SBs + pn * 8192 + bOff[j]);
    }
    const int pbA = p * 4096, pbB = p * 8192;
    bf16x8 af[4];
    #pragma unroll
    for (int rt = 0; rt < 4; ++rt)
      af[rt] = *(bf16x8*)&SAs[pbA + (wr * 64 + rt * 16 + m) * 32 + sR];
    #pragma unroll
    for (int ct = 0; ct < 8; ++ct) {
      bf16x8 bb = *(bf16x8*)&SBs[pbB + (wc * 128 + ct * 16 + m) * 32 + sR];
      #pragma unroll
      for (int rt = 0; rt < 4; ++rt)
        acc[rt][ct] = __builtin_amdgcn_mfma_f32_16x16x32_bf16(af[rt], bb, acc[rt][ct], 0, 0, 0);
    }
    p = (p == 2) ? 0 : p + 1;
  }
  asm volatile("" ::: "memory");

  // epilogue: token/target lookup via LDS aliased over the (now dead) stage
  __syncthreads();                 // all MFMA LDS reads done
  int* ptoks = (int*)pool;         // 128 ints
  int* tlocs = (int*)(pool + 1024);
  if (t < 128) {
    int idx = row0 + t;
    int tok = perm[cid * N_TOK + min(idx, count - 1)];
    ptoks[t] = tok;
    tlocs[t] = tgt[tok] - cstart;
  }
  __syncthreads();

  float bc[8];
  #pragma unroll
  for (int ct = 0; ct < 8; ++ct)
    bc[ct] = bias[min(col0 + wc * 128 + ct * 16 + m, csize - 1)];

  int tl[4][4];
  #pragma unroll
  for (int rt = 0; rt < 4; ++rt)
    #pragma unroll
    for (int rr = 0; rr < 4; ++rr)
      tl[rt][rr] = tlocs[wr * 64 + rt * 16 + q * 4 + rr];

  float run[4][4] = {{0.f}}, tcap[4][4] = {{0.f}};
  int tfnd[4][4] = {{0}};

  #pragma unroll
  for (int ct = 0; ct < 8; ++ct) {
    int colg = col0 + wc * 128 + ct * 16 + m;
    bool cok = colg < csize;
    #pragma unroll
    for (int rt = 0; rt < 4; ++rt)
      #pragma unroll
      for (int rr = 0; rr < 4; ++rr) {
        float val = acc[rt][ct][rr] + bc[ct];
        if (cok) {
          run[rt][rr] += __expf(val);
          if (tl[rt][rr] == colg) { tcap[rt][rr] = val; tfnd[rt][rr] = 1; }
        }
      }
  }

  #pragma unroll
  for (int rt = 0; rt < 4; ++rt)
    #pragma unroll
    for (int rr = 0; rr < 4; ++rr) {
      float v = run[rt][rr];
      v += __shfl_xor(v, 1, 64);
      v += __shfl_xor(v, 2, 64);
      v += __shfl_xor(v, 4, 64);
      v += __shfl_xor(v, 8, 64);
      int rowl = wr * 64 + rt * 16 + q * 4 + rr;
      if (row0 + rowl < count) {
        int tok = ptoks[rowl];
        if (m == 0) atomicAdd(&psum[tok], v);
        if (tfnd[rt][rr]) tlog[tok] = tcap[rt][rr];
      }
    }
}

__global__ __launch_bounds__(1024) void k_final(const float* __restrict__ psum,
                                                const float* __restrict__ tlog,
                                                float* __restrict__ out) {
  __shared__ float part[16];
  int t = threadIdx.x;
  float s = 0.f;
  for (int n = t; n < N_TOK; n += 1024) {
    float v = __logf(psum[n]) - tlog[n];
    out[1 + n] = v;
    s += v;
  }
  #pragma unroll
  for (int off = 32; off > 0; off >>= 1) s += __shfl_down(s, off, 64);
  if ((t & 63) == 0) part[t >> 6] = s;
  __syncthreads();
  if (t < 64) {
    float v = (t < 16) ? part[t] : 0.f;
    #pragma unroll
    for (int off = 8; off > 0; off >>= 1) v += __shfl_down(v, off, 64);
    if (t == 0) out[0] = v;
  }
}

extern "C" void kernel_launch(void* const* d_in, const int* in_sizes, int n_in,
                              void* d_out, int out_size, void* d_ws, size_t ws_size,
                              hipStream_t stream) {
  const float* x  = (const float*)d_in[0];
  const int* tgt  = (const int*)d_in[1];
  const float* p0 = (const float*)d_in[2];
  const float* w0 = (const float*)d_in[3];
  const float* b0 = (const float*)d_in[4];
  const float* p1 = (const float*)d_in[5];
  const float* w1 = (const float*)d_in[6];
  const float* b1 = (const float*)d_in[7];
  const float* p2 = (const float*)d_in[8];
  const float* w2 = (const float*)d_in[9];
  const float* b2 = (const float*)d_in[10];
  float* out = (float*)d_out;

  char* ws = (char*)d_ws;
  int* cnt            = (int*)(ws + 0);
  int* hoff           = (int*)(ws + 64);
  int* perm           = (int*)(ws + 256);                 // 98,304 B
  unsigned short* wb  = (unsigned short*)(ws + 131072);   // 51,331,584 B
  unsigned short* hb  = (unsigned short*)(ws + 51462656); // 16,777,216 B
  float* psum         = (float*)(ws + 68239872);          // 32,768 B
  float* tlog         = (float*)(ws + 68272640);          // 32,768 B

  k_setup<<<dim3(1), dim3(1024), 0, stream>>>(tgt, cnt, hoff, perm, psum);
  k_hc<<<dim3(512, 1, 4), dim3(256), 0, stream>>>(x, p0, p1, p2, w0, w1, w2,
                                                  perm, cnt, hoff, wb, hb);
  // x = 8 xcd-slots * g; g covers cpx(<=10) * ntile(<=64) -> 5120
  k_lse<<<dim3(5120, 1, 3), dim3(256), 0, stream>>>(hb, wb, b0, b1, b2, tgt, perm, cnt, hoff,
                                                    psum, tlog);
  k_final<<<dim3(1), dim3(1024), 0, stream>>>(psum, tlog, out);
}